// Round 3
// baseline (243.574 us; speedup 1.0000x reference)
//
#include <hip/hip_runtime.h>
#include <hip/hip_bf16.h>
#include <cstdint>
#include <cstddef>

// Problem constants (match reference)
#define N_EDGES_C 800000
#define N_NODES_C 50000
#define IN_CH_C   128
#define KDIM      256   // 2*IN_CH
#define HIDDEN_C  256
#define BM        64    // edges per block; 800000 % 64 == 0 -> 12500 blocks
#define THREADS   512   // 8 waves; wave w owns N-slice [w*32, w*32+32)

typedef __attribute__((ext_vector_type(8))) short sh8;
typedef __attribute__((ext_vector_type(4))) float f32x4;

__device__ __forceinline__ unsigned short f2bf(float f) {
  union { float f; unsigned u; } a; a.f = f;
  unsigned r = a.u + 0x7fffu + ((a.u >> 16) & 1u);  // RNE
  return (unsigned short)(r >> 16);
}

// z (fp32, N_NODES x 128) -> bf16 bits, 4 elems/thread
__global__ void cvt_z_kernel(const float* __restrict__ z,
                             unsigned short* __restrict__ zb) {
  int i = blockIdx.x * blockDim.x + threadIdx.x;
  float4 v = reinterpret_cast<const float4*>(z)[i];
  ushort4 o;
  o.x = f2bf(v.x); o.y = f2bf(v.y); o.z = f2bf(v.z); o.w = f2bf(v.w);
  reinterpret_cast<ushort4*>(zb)[i] = o;
}

// W1 [K=256][N=256] fp32 -> W1T [N][K] bf16 (so B-fragments are k-contiguous)
__global__ void cvt_w1t_kernel(const float* __restrict__ w1,
                               unsigned short* __restrict__ w1t) {
  int k = blockIdx.x;    // input row  (coalesced read)
  int n = threadIdx.x;   // output row
  w1t[(size_t)n * KDIM + k] = f2bf(w1[(size_t)k * HIDDEN_C + n]);
}

// Fused: gather -> (ef @ W1 + b1) -> relu -> @W2 + b2 -> sigmoid
// Block: 512 thr (8 waves), 64 edges. A-tile (64x256 bf16 = 32KB) in LDS,
// XOR-swizzled (byte ^= (row&7)<<4) -> conflict-free staging writes and
// fragment reads. Wave w computes N-slice [w*32, w*32+32).
template<bool ZBF>
__global__ __launch_bounds__(THREADS, 6) void decoder_kernel(
    const float* __restrict__ z,
    const unsigned short* __restrict__ zb,
    const int* __restrict__ ei,
    const unsigned short* __restrict__ w1t,
    const float* __restrict__ b1,
    const float* __restrict__ w2,
    const float* __restrict__ b2,
    float* __restrict__ out)
{
  __shared__ __align__(16) unsigned char lds[BM * 512];  // 32768 B

  const int tid  = threadIdx.x;
  const int wave = tid >> 6;
  const int lane = tid & 63;
  const int l15  = lane & 15;   // A row / B col / C col within 16-tile
  const int lg   = lane >> 4;   // k-subgroup (A/B), row-quad (C)
  const int base = blockIdx.x * BM;

  // ---- Stage A-tile: row e = t&63 (edge), 64B segment w8 = t>>6 ----
  // Logical: As[e][k] bf16, k in [0,256); byte col swizzled ^ ((e&7)<<4).
  {
    const int e   = tid & 63;
    const int w8  = tid >> 6;          // 0..7: which 64B of the 512B row
    const int nd  = w8 >> 2;           // node 0/1
    const int idx = ei[nd * N_EDGES_C + base + e];
    const int swzw = (e & 7) << 4;
    char* dstrow = (char*)lds + e * 512;
    if (ZBF) {
      const unsigned short* src = zb + (size_t)idx * IN_CH_C + (w8 & 3) * 32;
      sh8 t8[4];
#pragma unroll
      for (int i = 0; i < 4; ++i)
        t8[i] = *reinterpret_cast<const sh8*>(src + i * 8);
#pragma unroll
      for (int i = 0; i < 4; ++i)
        *reinterpret_cast<sh8*>(dstrow + ((w8 * 64 + i * 16) ^ swzw)) = t8[i];
    } else {
      const float* src = z + (size_t)idx * IN_CH_C + (w8 & 3) * 32;
      float4 tf[8];
#pragma unroll
      for (int i = 0; i < 8; ++i)
        tf[i] = reinterpret_cast<const float4*>(src)[i];
#pragma unroll
      for (int i = 0; i < 4; ++i) {
        sh8 o;
        const float4 x0 = tf[2 * i], x1 = tf[2 * i + 1];
        o[0] = (short)f2bf(x0.x); o[1] = (short)f2bf(x0.y);
        o[2] = (short)f2bf(x0.z); o[3] = (short)f2bf(x0.w);
        o[4] = (short)f2bf(x1.x); o[5] = (short)f2bf(x1.y);
        o[6] = (short)f2bf(x1.z); o[7] = (short)f2bf(x1.w);
        *reinterpret_cast<sh8*>(dstrow + ((w8 * 64 + i * 16) ^ swzw)) = o;
      }
    }
  }
  __syncthreads();

  const int n0  = wave * 32;
  const int swz = (l15 & 7) << 4;            // read-side row swizzle (row&7 == l15&7)
  // Two bases so every ds_read_b128 is base + compile-time immediate:
  // addr(kk,mt) = r*512 + ((kk*64 + lg*16) ^ swz)
  //             = Ebase + mt*8192 + kk*64                (kk even)
  //             = Ebase - 2*(swz&64) + mt*8192 + kk*64   (kk odd)
  const int Ebase = l15 * 512 + ((lg * 16) ^ swz);
  const int Obase = Ebase - ((swz & 64) << 1);

  const f32x4 fzero = {0.f, 0.f, 0.f, 0.f};
  f32x4 acc[4][2];
#pragma unroll
  for (int mt = 0; mt < 4; ++mt) {
    acc[mt][0] = fzero; acc[mt][1] = fzero;
  }

#pragma unroll
  for (int kk = 0; kk < 8; ++kk) {
    const int kOff = kk * 32 + lg * 8;
    sh8 bfrag[2];
#pragma unroll
    for (int nt = 0; nt < 2; ++nt)
      bfrag[nt] = *reinterpret_cast<const sh8*>(
          w1t + (size_t)(n0 + nt * 16 + l15) * KDIM + kOff);

    const int kbase = ((kk & 1) ? Obase : Ebase) + kk * 64;
#pragma unroll
    for (int mt = 0; mt < 4; ++mt) {
      const sh8 af = *reinterpret_cast<const sh8*>(
          (char*)lds + (kbase + mt * 8192));
      acc[mt][0] = __builtin_amdgcn_mfma_f32_16x16x32_bf16(
          af, bfrag[0], acc[mt][0], 0, 0, 0);
      acc[mt][1] = __builtin_amdgcn_mfma_f32_16x16x32_bf16(
          af, bfrag[1], acc[mt][1], 0, 0, 0);
    }
  }

  // Epilogue: bias + relu + W2 GEMV in registers.
  // C layout: col = n0 + nt*16 + l15, row (edge) = mt*16 + lg*4 + r
  float plog[4][4];
#pragma unroll
  for (int mt = 0; mt < 4; ++mt)
#pragma unroll
    for (int r = 0; r < 4; ++r)
      plog[mt][r] = 0.f;

#pragma unroll
  for (int nt = 0; nt < 2; ++nt) {
    const int j = n0 + nt * 16 + l15;
    const float b1v = b1[j];
    const float w2v = w2[j];
#pragma unroll
    for (int mt = 0; mt < 4; ++mt)
#pragma unroll
      for (int r = 0; r < 4; ++r) {
        float v = acc[mt][nt][r] + b1v;
        v = fmaxf(v, 0.f);
        plog[mt][r] = fmaf(v, w2v, plog[mt][r]);
      }
  }

  // Reduce over the 16 columns this wave's lg-group holds
#pragma unroll
  for (int s = 1; s < 16; s <<= 1)
#pragma unroll
    for (int mt = 0; mt < 4; ++mt)
#pragma unroll
      for (int r = 0; r < 4; ++r)
        plog[mt][r] += __shfl_xor(plog[mt][r], s, 64);

  // Cross-wave reduce (8 N-slices). Reuse the A-tile LDS (dead now).
  __syncthreads();   // all waves done reading As
  float* red = (float*)lds;          // [8][64]
  if (l15 == 0) {
#pragma unroll
    for (int mt = 0; mt < 4; ++mt)
#pragma unroll
      for (int r = 0; r < 4; ++r)
        red[wave * 64 + mt * 16 + lg * 4 + r] = plog[mt][r];
  }
  __syncthreads();
  if (tid < BM) {
    float s = b2[0];
#pragma unroll
    for (int w = 0; w < 8; ++w)
      s += red[w * 64 + tid];
    out[base + tid] = 1.f / (1.f + __expf(-s));
  }
}

extern "C" void kernel_launch(void* const* d_in, const int* in_sizes, int n_in,
                              void* d_out, int out_size, void* d_ws, size_t ws_size,
                              hipStream_t stream) {
  const float* z  = (const float*)d_in[0];
  const int*   ei = (const int*)d_in[1];
  const float* W1 = (const float*)d_in[2];
  const float* b1 = (const float*)d_in[3];
  const float* W2 = (const float*)d_in[4];
  const float* b2 = (const float*)d_in[5];
  float* out = (float*)d_out;

  unsigned short* w1t = (unsigned short*)d_ws;
  const size_t w1t_bytes = (size_t)HIDDEN_C * KDIM * sizeof(unsigned short); // 128 KB
  unsigned short* zb = (unsigned short*)((char*)d_ws + w1t_bytes);
  const size_t need = w1t_bytes + (size_t)N_NODES_C * IN_CH_C * sizeof(unsigned short);
  const bool zbf = (ws_size >= need);

  // Prep: W1^T bf16 (always; 128 KB fits any sane ws), z bf16 if ws allows.
  cvt_w1t_kernel<<<KDIM, HIDDEN_C, 0, stream>>>(W1, w1t);
  if (zbf) {
    const int n4 = N_NODES_C * IN_CH_C / 4;              // 1.6M float4 units
    cvt_z_kernel<<<n4 / 256, 256, 0, stream>>>(z, zb);
  }

  dim3 grid(N_EDGES_C / BM);  // 12500
  if (zbf)
    decoder_kernel<true><<<grid, THREADS, 0, stream>>>(z, zb, ei, w1t, b1, W2, b2, out);
  else
    decoder_kernel<false><<<grid, THREADS, 0, stream>>>(z, zb, ei, w1t, b1, W2, b2, out);
}

// Round 4
// 164.196 us; speedup vs baseline: 1.4834x; 1.4834x over previous
//
#include <hip/hip_runtime.h>
#include <hip/hip_bf16.h>
#include <cstdint>
#include <cstddef>

// Problem constants (match reference)
#define N_EDGES_C 800000
#define N_NODES_C 50000
#define IN_CH_C   128
#define KDIM      256    // 2*IN_CH
#define HIDDEN_C  256
#define TM        32     // edges per tile
#define NBLK      1000   // persistent blocks
#define NT        25     // tiles per block: 1000*25*32 = 800000 exactly
#define THREADS   512    // 8 waves; wave w owns N-slice [w*32, w*32+32)

typedef __attribute__((ext_vector_type(8))) short sh8;
typedef __attribute__((ext_vector_type(4))) float f32x4;

__device__ __forceinline__ unsigned short f2bf(float f) {
  union { float f; unsigned u; } a; a.f = f;
  unsigned r = a.u + 0x7fffu + ((a.u >> 16) & 1u);  // RNE
  return (unsigned short)(r >> 16);
}

__device__ __forceinline__ void glds16(const unsigned short* g, void* l) {
  __builtin_amdgcn_global_load_lds(
      (const __attribute__((address_space(1))) unsigned int*)g,
      (__attribute__((address_space(3))) unsigned int*)l, 16, 0, 0);
}

// z (fp32, N_NODES x 128) -> bf16 bits, 4 elems/thread
__global__ void cvt_z_kernel(const float* __restrict__ z,
                             unsigned short* __restrict__ zb) {
  int i = blockIdx.x * blockDim.x + threadIdx.x;
  float4 v = reinterpret_cast<const float4*>(z)[i];
  ushort4 o;
  o.x = f2bf(v.x); o.y = f2bf(v.y); o.z = f2bf(v.z); o.w = f2bf(v.w);
  reinterpret_cast<ushort4*>(zb)[i] = o;
}

// W1 [K=256][N=256] fp32 -> W1T [N][K] bf16
__global__ void cvt_w1t_kernel(const float* __restrict__ w1,
                               unsigned short* __restrict__ w1t) {
  int k = blockIdx.x;
  int n = threadIdx.x;
  w1t[(size_t)n * KDIM + k] = f2bf(w1[(size_t)k * HIDDEN_C + n]);
}

// Persistent fused kernel. Per block: 25 tiles x 32 edges.
// B (W1T slice) in registers; A staged via global_load_lds with pre-swizzled
// gather source (linear LDS dest, XOR involution byte^=(row&7)<<4 on read).
// Pipeline: raw s_barrier + counted vmcnt(4); 1 barrier + 1 waitcnt per tile.
__global__ __launch_bounds__(THREADS, 4) void decoder_persist(
    const unsigned short* __restrict__ zb,
    const int* __restrict__ ei,
    const unsigned short* __restrict__ w1t,
    const float* __restrict__ b1,
    const float* __restrict__ w2,
    const float* __restrict__ b2,
    float* __restrict__ out)
{
  __shared__ __align__(16) unsigned char lds[3 * 16384 + 2048]; // 3 stage bufs + red[2][8][32]
  float* red = (float*)(lds + 3 * 16384);

  const int tid = threadIdx.x;
  const int w   = tid >> 6;
  const int l   = tid & 63;
  const int l15 = l & 15;
  const int lg  = l >> 4;
  const int n0  = w * 32;
  const int tb  = blockIdx.x * (NT * TM);

  // ---- lane-fixed staging geometry (dest linear: d=(2w+i)*1024 + l*16) ----
  const int nd   = (l >> 4) & 1;           // node half this lane fetches
  const int eo0  = 4 * w + (l >> 5);       // edge row, i=0
  const int eo1  = eo0 + 2;                // edge row, i=1
  const int sc   = (l & 31) * 16;          // stored byte col
  const int off0 = (sc ^ ((eo0 & 7) << 4)) & 255;  // byte off in node row
  const int off1 = (sc ^ ((eo1 & 7) << 4)) & 255;
  const int* eip0 = ei + (size_t)nd * N_EDGES_C + tb + eo0;
  const int* eip1 = ei + (size_t)nd * N_EDGES_C + tb + eo1;

  // ---- B preload: 16 x b128, held for the whole block ----
  sh8 bfr[2][8];
#pragma unroll
  for (int nt = 0; nt < 2; ++nt)
#pragma unroll
    for (int kk = 0; kk < 8; ++kk)
      bfr[nt][kk] = *reinterpret_cast<const sh8*>(
          w1t + (size_t)(n0 + nt * 16 + l15) * KDIM + kk * 32 + lg * 8);

  const float b1v0 = b1[n0 + l15],      b1v1 = b1[n0 + 16 + l15];
  const float w2v0 = w2[n0 + l15],      w2v1 = w2[n0 + 16 + l15];
  const float b2v  = b2[0];

  // read-side swizzle bases (same involution as staging source)
  const int b2b = (l15 >> 2) & 1;
  const int Eb  = l15 * 512 + 64 * b2b + ((lg * 16) ^ ((l15 & 3) << 4));
  const int Ob  = Eb - 128 * b2b;

  // ---- prologue: I(0); I(1); G(0); I(2); G(1)  [keeps I older than next G] ----
  int ia0 = eip0[0],      ia1 = eip1[0];
  __builtin_amdgcn_sched_barrier(0);
  int ib0 = eip0[TM],     ib1 = eip1[TM];
  __builtin_amdgcn_sched_barrier(0);
  glds16(zb + (size_t)ia0 * IN_CH_C + (off0 >> 1), lds + 0 * 16384 + (2 * w + 0) * 1024);
  glds16(zb + (size_t)ia1 * IN_CH_C + (off1 >> 1), lds + 0 * 16384 + (2 * w + 1) * 1024);
  __builtin_amdgcn_sched_barrier(0);
  int jc0 = eip0[2 * TM], jc1 = eip1[2 * TM];     // idx for tile 2, consumed at t=0
  __builtin_amdgcn_sched_barrier(0);
  glds16(zb + (size_t)ib0 * IN_CH_C + (off0 >> 1), lds + 1 * 16384 + (2 * w + 0) * 1024);
  glds16(zb + (size_t)ib1 * IN_CH_C + (off1 >> 1), lds + 1 * 16384 + (2 * w + 1) * 1024);
  __builtin_amdgcn_sched_barrier(0);

  int cur = 0, nx1 = 16384, nx2 = 32768;   // rotating stage-buffer offsets

#pragma unroll 1
  for (int t = 0; t < NT; ++t) {
    __builtin_amdgcn_sched_barrier(0);
    asm volatile("s_waitcnt vmcnt(4) lgkmcnt(0)" ::: "memory"); // stage(t) landed; keep stage(t+1)+idx in flight
    __builtin_amdgcn_s_barrier();
    __builtin_amdgcn_sched_barrier(0);

    // I: idx for tile t+3 (clamped; keeps vmcnt counts uniform incl. tail)
    const int tn = (t + 3 < NT) ? (t + 3) : (NT - 1);
    int ni0 = eip0[tn * TM];
    int ni1 = eip1[tn * TM];
    __builtin_amdgcn_sched_barrier(0);

    // G: stage tile t+2 (clamped idx) into buf nx2
    glds16(zb + (size_t)jc0 * IN_CH_C + (off0 >> 1), lds + nx2 + (2 * w + 0) * 1024);
    glds16(zb + (size_t)jc1 * IN_CH_C + (off1 >> 1), lds + nx2 + (2 * w + 1) * 1024);
    __builtin_amdgcn_sched_barrier(0);

    // ---- compute tile t from buf cur ----
    const f32x4 fz = {0.f, 0.f, 0.f, 0.f};
    f32x4 acc[2][2] = {{fz, fz}, {fz, fz}};
#pragma unroll
    for (int kk = 0; kk < 8; ++kk) {
      const int kb_ = ((kk & 1) ? Ob : Eb) + kk * 64;
#pragma unroll
      for (int mt = 0; mt < 2; ++mt) {
        const sh8 af = *reinterpret_cast<const sh8*>(lds + cur + kb_ + mt * 8192);
        acc[mt][0] = __builtin_amdgcn_mfma_f32_16x16x32_bf16(af, bfr[0][kk], acc[mt][0], 0, 0, 0);
        acc[mt][1] = __builtin_amdgcn_mfma_f32_16x16x32_bf16(af, bfr[1][kk], acc[mt][1], 0, 0, 0);
      }
    }

    // epilogue: bias+relu+W2 partials, reduce over 16 cols, stash to red[t&1]
    float pl[2][4];
#pragma unroll
    for (int mt = 0; mt < 2; ++mt)
#pragma unroll
      for (int r = 0; r < 4; ++r) {
        float v0 = fmaxf(acc[mt][0][r] + b1v0, 0.f);
        float v1 = fmaxf(acc[mt][1][r] + b1v1, 0.f);
        pl[mt][r] = v0 * w2v0 + v1 * w2v1;
      }
#pragma unroll
    for (int s = 1; s < 16; s <<= 1)
#pragma unroll
      for (int mt = 0; mt < 2; ++mt)
#pragma unroll
        for (int r = 0; r < 4; ++r)
          pl[mt][r] += __shfl_xor(pl[mt][r], s, 64);
    if (l15 == 0) {
#pragma unroll
      for (int mt = 0; mt < 2; ++mt) {
        float4 v = make_float4(pl[mt][0], pl[mt][1], pl[mt][2], pl[mt][3]);
        *reinterpret_cast<float4*>(&red[(t & 1) * 256 + w * 32 + mt * 16 + lg * 4]) = v;
      }
    }

    // finalize tile t-1 (its red parity is stable: written before this iter's barrier)
    if (t > 0 && tid < TM) {
      float s = b2v;
#pragma unroll
      for (int ww = 0; ww < 8; ++ww)
        s += red[((t - 1) & 1) * 256 + ww * 32 + tid];
      out[tb + (t - 1) * TM + tid] = 1.f / (1.f + __expf(-s));
    }

    jc0 = ni0; jc1 = ni1;
    int tmp = cur; cur = nx1; nx1 = nx2; nx2 = tmp;
  }

  // final flush: tile NT-1
  __builtin_amdgcn_sched_barrier(0);
  asm volatile("s_waitcnt lgkmcnt(0)" ::: "memory");
  __builtin_amdgcn_s_barrier();
  __builtin_amdgcn_sched_barrier(0);
  if (tid < TM) {
    float s = b2v;
#pragma unroll
    for (int ww = 0; ww < 8; ++ww)
      s += red[((NT - 1) & 1) * 256 + ww * 32 + tid];
    out[tb + (NT - 1) * TM + tid] = 1.f / (1.f + __expf(-s));
  }
  asm volatile("s_waitcnt vmcnt(0)" ::: "memory");  // drain clamped tail DMAs
}

// ---------------- fallback (no-workspace) path: R3 kernel ----------------
#define BM 64
__global__ __launch_bounds__(512, 6) void decoder_fb(
    const float* __restrict__ z, const int* __restrict__ ei,
    const unsigned short* __restrict__ w1t, const float* __restrict__ b1,
    const float* __restrict__ w2, const float* __restrict__ b2,
    float* __restrict__ out)
{
  __shared__ __align__(16) unsigned char lds[BM * 512];
  const int tid = threadIdx.x, wave = tid >> 6, lane = tid & 63;
  const int l15 = lane & 15, lg = lane >> 4, base = blockIdx.x * BM;
  {
    const int e = tid & 63, w8 = tid >> 6, nd = w8 >> 2;
    const int idx = ei[nd * N_EDGES_C + base + e];
    const int swzw = (e & 7) << 4;
    char* dstrow = (char*)lds + e * 512;
    const float* src = z + (size_t)idx * IN_CH_C + (w8 & 3) * 32;
    float4 tf[8];
#pragma unroll
    for (int i = 0; i < 8; ++i) tf[i] = reinterpret_cast<const float4*>(src)[i];
#pragma unroll
    for (int i = 0; i < 4; ++i) {
      sh8 o; const float4 x0 = tf[2*i], x1 = tf[2*i+1];
      o[0]=(short)f2bf(x0.x); o[1]=(short)f2bf(x0.y); o[2]=(short)f2bf(x0.z); o[3]=(short)f2bf(x0.w);
      o[4]=(short)f2bf(x1.x); o[5]=(short)f2bf(x1.y); o[6]=(short)f2bf(x1.z); o[7]=(short)f2bf(x1.w);
      *reinterpret_cast<sh8*>(dstrow + ((w8 * 64 + i * 16) ^ swzw)) = o;
    }
  }
  __syncthreads();
  const int n0 = wave * 32;
  const int swz = (l15 & 7) << 4;
  const int Ebase = l15 * 512 + ((lg * 16) ^ swz);
  const int Obase = Ebase - ((swz & 64) << 1);
  const f32x4 fz = {0.f,0.f,0.f,0.f};
  f32x4 acc[4][2];
#pragma unroll
  for (int mt = 0; mt < 4; ++mt) { acc[mt][0] = fz; acc[mt][1] = fz; }
#pragma unroll
  for (int kk = 0; kk < 8; ++kk) {
    const int kOff = kk * 32 + lg * 8;
    sh8 bfrag[2];
#pragma unroll
    for (int nt = 0; nt < 2; ++nt)
      bfrag[nt] = *reinterpret_cast<const sh8*>(w1t + (size_t)(n0 + nt*16 + l15) * KDIM + kOff);
    const int kbase = ((kk & 1) ? Obase : Ebase) + kk * 64;
#pragma unroll
    for (int mt = 0; mt < 4; ++mt) {
      const sh8 af = *reinterpret_cast<const sh8*>((char*)lds + (kbase + mt * 8192));
      acc[mt][0] = __builtin_amdgcn_mfma_f32_16x16x32_bf16(af, bfrag[0], acc[mt][0], 0, 0, 0);
      acc[mt][1] = __builtin_amdgcn_mfma_f32_16x16x32_bf16(af, bfrag[1], acc[mt][1], 0, 0, 0);
    }
  }
  float plog[4][4];
#pragma unroll
  for (int mt = 0; mt < 4; ++mt)
#pragma unroll
    for (int r = 0; r < 4; ++r) plog[mt][r] = 0.f;
#pragma unroll
  for (int nt = 0; nt < 2; ++nt) {
    const int j = n0 + nt * 16 + l15;
    const float b1v = b1[j], w2v = w2[j];
#pragma unroll
    for (int mt = 0; mt < 4; ++mt)
#pragma unroll
      for (int r = 0; r < 4; ++r)
        plog[mt][r] = fmaf(fmaxf(acc[mt][nt][r] + b1v, 0.f), w2v, plog[mt][r]);
  }
#pragma unroll
  for (int s = 1; s < 16; s <<= 1)
#pragma unroll
    for (int mt = 0; mt < 4; ++mt)
#pragma unroll
      for (int r = 0; r < 4; ++r)
        plog[mt][r] += __shfl_xor(plog[mt][r], s, 64);
  __syncthreads();
  float* red = (float*)lds;
  if (l15 == 0)
#pragma unroll
    for (int mt = 0; mt < 4; ++mt)
#pragma unroll
      for (int r = 0; r < 4; ++r)
        red[wave * 64 + mt * 16 + lg * 4 + r] = plog[mt][r];
  __syncthreads();
  if (tid < BM) {
    float s = b2[0];
#pragma unroll
    for (int w = 0; w < 8; ++w) s += red[w * 64 + tid];
    out[base + tid] = 1.f / (1.f + __expf(-s));
  }
}

extern "C" void kernel_launch(void* const* d_in, const int* in_sizes, int n_in,
                              void* d_out, int out_size, void* d_ws, size_t ws_size,
                              hipStream_t stream) {
  const float* z  = (const float*)d_in[0];
  const int*   ei = (const int*)d_in[1];
  const float* W1 = (const float*)d_in[2];
  const float* b1 = (const float*)d_in[3];
  const float* W2 = (const float*)d_in[4];
  const float* b2 = (const float*)d_in[5];
  float* out = (float*)d_out;

  unsigned short* w1t = (unsigned short*)d_ws;
  const size_t w1t_bytes = (size_t)HIDDEN_C * KDIM * sizeof(unsigned short); // 128 KB
  unsigned short* zb = (unsigned short*)((char*)d_ws + w1t_bytes);
  const size_t need = w1t_bytes + (size_t)N_NODES_C * IN_CH_C * sizeof(unsigned short);
  const bool zbf = (ws_size >= need);

  cvt_w1t_kernel<<<KDIM, HIDDEN_C, 0, stream>>>(W1, w1t);
  if (zbf) {
    const int n4 = N_NODES_C * IN_CH_C / 4;
    cvt_z_kernel<<<n4 / 256, 256, 0, stream>>>(z, zb);
    decoder_persist<<<NBLK, THREADS, 0, stream>>>(zb, ei, w1t, b1, W2, b2, out);
  } else {
    decoder_fb<<<N_EDGES_C / BM, 512, 0, stream>>>(z, ei, w1t, b1, W2, b2, out);
  }
}

// Round 5
// 158.407 us; speedup vs baseline: 1.5376x; 1.0365x over previous
//
#include <hip/hip_runtime.h>
#include <hip/hip_bf16.h>
#include <cstdint>
#include <cstddef>

// Problem constants (match reference)
#define N_EDGES_C 800000
#define N_NODES_C 50000
#define IN_CH_C   128
#define KDIM      256    // 2*IN_CH
#define HIDDEN_C  256
#define TM        32     // edges per tile
#define NBLK      512    // 2 blocks/CU exactly -> all blocks co-start, no tail
#define THREADS   512    // 8 waves; wave w owns N-slice [w*32, w*32+32)
// tile split: 424 blocks x 49 tiles + 88 blocks x 48 tiles = 25000 tiles

typedef __attribute__((ext_vector_type(8))) short sh8;
typedef __attribute__((ext_vector_type(4))) float f32x4;

__device__ __forceinline__ unsigned short f2bf(float f) {
  union { float f; unsigned u; } a; a.f = f;
  unsigned r = a.u + 0x7fffu + ((a.u >> 16) & 1u);  // RNE
  return (unsigned short)(r >> 16);
}

__device__ __forceinline__ void glds16(const unsigned short* g, void* l) {
  __builtin_amdgcn_global_load_lds(
      (const __attribute__((address_space(1))) unsigned int*)g,
      (__attribute__((address_space(3))) unsigned int*)l, 16, 0, 0);
}

// z (fp32, N_NODES x 128) -> bf16 bits, 4 elems/thread
__global__ void cvt_z_kernel(const float* __restrict__ z,
                             unsigned short* __restrict__ zb) {
  int i = blockIdx.x * blockDim.x + threadIdx.x;
  float4 v = reinterpret_cast<const float4*>(z)[i];
  ushort4 o;
  o.x = f2bf(v.x); o.y = f2bf(v.y); o.z = f2bf(v.z); o.w = f2bf(v.w);
  reinterpret_cast<ushort4*>(zb)[i] = o;
}

// W1 [K=256][N=256] fp32 -> W1T [N][K] bf16
__global__ void cvt_w1t_kernel(const float* __restrict__ w1,
                               unsigned short* __restrict__ w1t) {
  int k = blockIdx.x;
  int n = threadIdx.x;
  w1t[(size_t)n * KDIM + k] = f2bf(w1[(size_t)k * HIDDEN_C + n]);
}

// Persistent fused kernel, 512 blocks (2/CU). Per block: 48-49 tiles x 32 edges.
// B (W1T slice) in registers; A staged via global_load_lds with pre-swizzled
// gather source (linear LDS dest, XOR involution byte^=(row&7)<<4 on read).
// Pipeline: raw s_barrier + counted vmcnt(4); 1 barrier + 1 waitcnt per tile.
__global__ __launch_bounds__(THREADS, 4) void decoder_persist(
    const unsigned short* __restrict__ zb,
    const int* __restrict__ ei,
    const unsigned short* __restrict__ w1t,
    const float* __restrict__ b1,
    const float* __restrict__ w2,
    const float* __restrict__ b2,
    float* __restrict__ out)
{
  __shared__ __align__(16) unsigned char lds[3 * 16384 + 2048]; // 3 stage bufs + red[2][8][32]
  float* red = (float*)(lds + 3 * 16384);

  const int tid = threadIdx.x;
  const int w   = tid >> 6;
  const int l   = tid & 63;
  const int l15 = l & 15;
  const int lg  = l >> 4;
  const int n0  = w * 32;

  // per-block tile range: blocks [0,424): 49 tiles; [424,512): 48 tiles
  const int b    = blockIdx.x;
  const bool big = (b < 424);
  const int ntb  = big ? 49 : 48;
  const int S    = big ? (49 * b) : (49 * 424 + 48 * (b - 424));
  const int tb   = S * TM;   // first edge of this block

  // ---- lane-fixed staging geometry (dest linear: d=(2w+i)*1024 + l*16) ----
  const int nd   = (l >> 4) & 1;           // node half this lane fetches
  const int eo0  = 4 * w + (l >> 5);       // edge row, i=0
  const int eo1  = eo0 + 2;                // edge row, i=1
  const int sc   = (l & 31) * 16;          // stored byte col
  const int off0 = (sc ^ ((eo0 & 7) << 4)) & 255;  // byte off in node row
  const int off1 = (sc ^ ((eo1 & 7) << 4)) & 255;
  const int* eip0 = ei + (size_t)nd * N_EDGES_C + tb + eo0;
  const int* eip1 = ei + (size_t)nd * N_EDGES_C + tb + eo1;

  // ---- B preload: 16 x b128, held for the whole block ----
  sh8 bfr[2][8];
#pragma unroll
  for (int nt = 0; nt < 2; ++nt)
#pragma unroll
    for (int kk = 0; kk < 8; ++kk)
      bfr[nt][kk] = *reinterpret_cast<const sh8*>(
          w1t + (size_t)(n0 + nt * 16 + l15) * KDIM + kk * 32 + lg * 8);

  const float b1v0 = b1[n0 + l15],      b1v1 = b1[n0 + 16 + l15];
  const float w2v0 = w2[n0 + l15],      w2v1 = w2[n0 + 16 + l15];
  const float b2v  = b2[0];

  // read-side swizzle bases (same involution as staging source)
  const int b2b = (l15 >> 2) & 1;
  const int Eb  = l15 * 512 + 64 * b2b + ((lg * 16) ^ ((l15 & 3) << 4));
  const int Ob  = Eb - 128 * b2b;

  // ---- prologue: I(0); I(1); G(0); I(2); G(1)  [keeps I older than next G] ----
  int ia0 = eip0[0],      ia1 = eip1[0];
  __builtin_amdgcn_sched_barrier(0);
  int ib0 = eip0[TM],     ib1 = eip1[TM];
  __builtin_amdgcn_sched_barrier(0);
  glds16(zb + (size_t)ia0 * IN_CH_C + (off0 >> 1), lds + 0 * 16384 + (2 * w + 0) * 1024);
  glds16(zb + (size_t)ia1 * IN_CH_C + (off1 >> 1), lds + 0 * 16384 + (2 * w + 1) * 1024);
  __builtin_amdgcn_sched_barrier(0);
  int jc0 = eip0[2 * TM], jc1 = eip1[2 * TM];     // idx for tile 2, consumed at t=0
  __builtin_amdgcn_sched_barrier(0);
  glds16(zb + (size_t)ib0 * IN_CH_C + (off0 >> 1), lds + 1 * 16384 + (2 * w + 0) * 1024);
  glds16(zb + (size_t)ib1 * IN_CH_C + (off1 >> 1), lds + 1 * 16384 + (2 * w + 1) * 1024);
  __builtin_amdgcn_sched_barrier(0);

  int cur = 0, nx1 = 16384, nx2 = 32768;   // rotating stage-buffer offsets

#pragma unroll 1
  for (int t = 0; t < ntb; ++t) {
    __builtin_amdgcn_sched_barrier(0);
    asm volatile("s_waitcnt vmcnt(4) lgkmcnt(0)" ::: "memory"); // stage(t) landed; keep stage(t+1)+idx in flight
    __builtin_amdgcn_s_barrier();
    __builtin_amdgcn_sched_barrier(0);

    // I: idx for tile t+3 (clamped; keeps vmcnt counts uniform incl. tail)
    const int tn = (t + 3 < ntb) ? (t + 3) : (ntb - 1);
    int ni0 = eip0[tn * TM];
    int ni1 = eip1[tn * TM];
    __builtin_amdgcn_sched_barrier(0);

    // G: stage tile t+2 (clamped idx) into buf nx2
    glds16(zb + (size_t)jc0 * IN_CH_C + (off0 >> 1), lds + nx2 + (2 * w + 0) * 1024);
    glds16(zb + (size_t)jc1 * IN_CH_C + (off1 >> 1), lds + nx2 + (2 * w + 1) * 1024);
    __builtin_amdgcn_sched_barrier(0);

    // ---- compute tile t from buf cur ----
    const f32x4 fz = {0.f, 0.f, 0.f, 0.f};
    f32x4 acc[2][2] = {{fz, fz}, {fz, fz}};
    __builtin_amdgcn_s_setprio(1);
#pragma unroll
    for (int kk = 0; kk < 8; ++kk) {
      const int kb_ = ((kk & 1) ? Ob : Eb) + kk * 64;
#pragma unroll
      for (int mt = 0; mt < 2; ++mt) {
        const sh8 af = *reinterpret_cast<const sh8*>(lds + cur + kb_ + mt * 8192);
        acc[mt][0] = __builtin_amdgcn_mfma_f32_16x16x32_bf16(af, bfr[0][kk], acc[mt][0], 0, 0, 0);
        acc[mt][1] = __builtin_amdgcn_mfma_f32_16x16x32_bf16(af, bfr[1][kk], acc[mt][1], 0, 0, 0);
      }
    }
    __builtin_amdgcn_s_setprio(0);

    // epilogue: bias+relu+W2 partials, reduce over 16 cols, stash to red[t&1]
    float pl[2][4];
#pragma unroll
    for (int mt = 0; mt < 2; ++mt)
#pragma unroll
      for (int r = 0; r < 4; ++r) {
        float v0 = fmaxf(acc[mt][0][r] + b1v0, 0.f);
        float v1 = fmaxf(acc[mt][1][r] + b1v1, 0.f);
        pl[mt][r] = v0 * w2v0 + v1 * w2v1;
      }
#pragma unroll
    for (int s = 1; s < 16; s <<= 1)
#pragma unroll
      for (int mt = 0; mt < 2; ++mt)
#pragma unroll
        for (int r = 0; r < 4; ++r)
          pl[mt][r] += __shfl_xor(pl[mt][r], s, 64);
    if (l15 == 0) {
#pragma unroll
      for (int mt = 0; mt < 2; ++mt) {
        float4 v = make_float4(pl[mt][0], pl[mt][1], pl[mt][2], pl[mt][3]);
        *reinterpret_cast<float4*>(&red[(t & 1) * 256 + w * 32 + mt * 16 + lg * 4]) = v;
      }
    }

    // finalize tile t-1 (its red parity is stable: written before this iter's barrier)
    if (t > 0 && tid < TM) {
      float s = b2v;
#pragma unroll
      for (int ww = 0; ww < 8; ++ww)
        s += red[((t - 1) & 1) * 256 + ww * 32 + tid];
      out[tb + (t - 1) * TM + tid] = 1.f / (1.f + __expf(-s));
    }

    jc0 = ni0; jc1 = ni1;
    int tmp = cur; cur = nx1; nx1 = nx2; nx2 = tmp;
  }

  // final flush: tile ntb-1
  __builtin_amdgcn_sched_barrier(0);
  asm volatile("s_waitcnt lgkmcnt(0)" ::: "memory");
  __builtin_amdgcn_s_barrier();
  __builtin_amdgcn_sched_barrier(0);
  if (tid < TM) {
    float s = b2v;
#pragma unroll
    for (int ww = 0; ww < 8; ++ww)
      s += red[((ntb - 1) & 1) * 256 + ww * 32 + tid];
    out[tb + (ntb - 1) * TM + tid] = 1.f / (1.f + __expf(-s));
  }
  asm volatile("s_waitcnt vmcnt(0)" ::: "memory");  // drain clamped tail DMAs
}

// ---------------- fallback (no-workspace) path: R3 kernel ----------------
#define BM 64
__global__ __launch_bounds__(512, 6) void decoder_fb(
    const float* __restrict__ z, const int* __restrict__ ei,
    const unsigned short* __restrict__ w1t, const float* __restrict__ b1,
    const float* __restrict__ w2, const float* __restrict__ b2,
    float* __restrict__ out)
{
  __shared__ __align__(16) unsigned char lds[BM * 512];
  const int tid = threadIdx.x, wave = tid >> 6, lane = tid & 63;
  const int l15 = lane & 15, lg = lane >> 4, base = blockIdx.x * BM;
  {
    const int e = tid & 63, w8 = tid >> 6, nd = w8 >> 2;
    const int idx = ei[nd * N_EDGES_C + base + e];
    const int swzw = (e & 7) << 4;
    char* dstrow = (char*)lds + e * 512;
    const float* src = z + (size_t)idx * IN_CH_C + (w8 & 3) * 32;
    float4 tf[8];
#pragma unroll
    for (int i = 0; i < 8; ++i) tf[i] = reinterpret_cast<const float4*>(src)[i];
#pragma unroll
    for (int i = 0; i < 4; ++i) {
      sh8 o; const float4 x0 = tf[2*i], x1 = tf[2*i+1];
      o[0]=(short)f2bf(x0.x); o[1]=(short)f2bf(x0.y); o[2]=(short)f2bf(x0.z); o[3]=(short)f2bf(x0.w);
      o[4]=(short)f2bf(x1.x); o[5]=(short)f2bf(x1.y); o[6]=(short)f2bf(x1.z); o[7]=(short)f2bf(x1.w);
      *reinterpret_cast<sh8*>(dstrow + ((w8 * 64 + i * 16) ^ swzw)) = o;
    }
  }
  __syncthreads();
  const int n0 = wave * 32;
  const int swz = (l15 & 7) << 4;
  const int Ebase = l15 * 512 + ((lg * 16) ^ swz);
  const int Obase = Ebase - ((swz & 64) << 1);
  const f32x4 fz = {0.f,0.f,0.f,0.f};
  f32x4 acc[4][2];
#pragma unroll
  for (int mt = 0; mt < 4; ++mt) { acc[mt][0] = fz; acc[mt][1] = fz; }
#pragma unroll
  for (int kk = 0; kk < 8; ++kk) {
    const int kOff = kk * 32 + lg * 8;
    sh8 bfrag[2];
#pragma unroll
    for (int nt = 0; nt < 2; ++nt)
      bfrag[nt] = *reinterpret_cast<const sh8*>(w1t + (size_t)(n0 + nt*16 + l15) * KDIM + kOff);
    const int kbase = ((kk & 1) ? Obase : Ebase) + kk * 64;
#pragma unroll
    for (int mt = 0; mt < 4; ++mt) {
      const sh8 af = *reinterpret_cast<const sh8*>((char*)lds + (kbase + mt * 8192));
      acc[mt][0] = __builtin_amdgcn_mfma_f32_16x16x32_bf16(af, bfrag[0], acc[mt][0], 0, 0, 0);
      acc[mt][1] = __builtin_amdgcn_mfma_f32_16x16x32_bf16(af, bfrag[1], acc[mt][1], 0, 0, 0);
    }
  }
  float plog[4][4];
#pragma unroll
  for (int mt = 0; mt < 4; ++mt)
#pragma unroll
    for (int r = 0; r < 4; ++r) plog[mt][r] = 0.f;
#pragma unroll
  for (int nt = 0; nt < 2; ++nt) {
    const int j = n0 + nt * 16 + l15;
    const float b1v = b1[j], w2v = w2[j];
#pragma unroll
    for (int mt = 0; mt < 4; ++mt)
#pragma unroll
      for (int r = 0; r < 4; ++r)
        plog[mt][r] = fmaf(fmaxf(acc[mt][nt][r] + b1v, 0.f), w2v, plog[mt][r]);
  }
#pragma unroll
  for (int s = 1; s < 16; s <<= 1)
#pragma unroll
    for (int mt = 0; mt < 4; ++mt)
#pragma unroll
      for (int r = 0; r < 4; ++r)
        plog[mt][r] += __shfl_xor(plog[mt][r], s, 64);
  __syncthreads();
  float* red = (float*)lds;
  if (l15 == 0)
#pragma unroll
    for (int mt = 0; mt < 4; ++mt)
#pragma unroll
      for (int r = 0; r < 4; ++r)
        red[wave * 64 + mt * 16 + lg * 4 + r] = plog[mt][r];
  __syncthreads();
  if (tid < BM) {
    float s = b2[0];
#pragma unroll
    for (int w = 0; w < 8; ++w) s += red[w * 64 + tid];
    out[base + tid] = 1.f / (1.f + __expf(-s));
  }
}

extern "C" void kernel_launch(void* const* d_in, const int* in_sizes, int n_in,
                              void* d_out, int out_size, void* d_ws, size_t ws_size,
                              hipStream_t stream) {
  const float* z  = (const float*)d_in[0];
  const int*   ei = (const int*)d_in[1];
  const float* W1 = (const float*)d_in[2];
  const float* b1 = (const float*)d_in[3];
  const float* W2 = (const float*)d_in[4];
  const float* b2 = (const float*)d_in[5];
  float* out = (float*)d_out;

  unsigned short* w1t = (unsigned short*)d_ws;
  const size_t w1t_bytes = (size_t)HIDDEN_C * KDIM * sizeof(unsigned short); // 128 KB
  unsigned short* zb = (unsigned short*)((char*)d_ws + w1t_bytes);
  const size_t need = w1t_bytes + (size_t)N_NODES_C * IN_CH_C * sizeof(unsigned short);
  const bool zbf = (ws_size >= need);

  cvt_w1t_kernel<<<KDIM, HIDDEN_C, 0, stream>>>(W1, w1t);
  if (zbf) {
    const int n4 = N_NODES_C * IN_CH_C / 4;
    cvt_z_kernel<<<n4 / 256, 256, 0, stream>>>(z, zb);
    decoder_persist<<<NBLK, THREADS, 0, stream>>>(zb, ei, w1t, b1, W2, b2, out);
  } else {
    decoder_fb<<<N_EDGES_C / BM, 512, 0, stream>>>(z, ei, w1t, b1, W2, b2, out);
  }
}